// Round 3
// baseline (820.392 us; speedup 1.0000x reference)
//
#include <hip/hip_runtime.h>
#include <hip/hip_bf16.h>
#include <stdint.h>

#define NB      256
#define NN      100
#define NE      1600
#define NEL     1700
#define FIN     2048
#define HG      512
#define DG      256
#define PO      1024
#define KTOP    50
#define NEG_SLOPE 0.2f

typedef __attribute__((ext_vector_type(8))) short bf16x8;
typedef __attribute__((ext_vector_type(4))) float f32x4;
typedef unsigned int u32;

// fp32 -> bf16 (RNE) bit helpers
__device__ inline ushort f2bf(float x) {
  unsigned u = __float_as_uint(x);
  return (ushort)((u + 0x7fffu + ((u >> 16) & 1u)) >> 16);
}
__device__ inline float bf2f(ushort b) {
  return __uint_as_float((unsigned)b << 16);
}

// global -> LDS direct copy, 16B per lane. LDS dest must be wave-uniform
// base; HW writes base + lane*16. Global src is per-lane.
__device__ inline void gl16(const void* g, void* l) {
  __builtin_amdgcn_global_load_lds(
      (const __attribute__((address_space(1))) u32*)g,
      (__attribute__((address_space(3))) u32*)l, 16, 0, 0);
}

// XOR swizzle on 16B granularity within a 64B (32-ushort) row:
// logical element (row, kc) -> stored offset. Spreads the column-slice
// ds_read_b128 pattern across all bank quads (2-way max = free).
__device__ inline int swz(int row, int kc) {
  return row * 32 + ((((kc >> 3) ^ (row & 3)) << 3) | (kc & 7));
}

// ---------------------------------------------------------------------------
// Transpose + hi/lo split of weight W[K][N] -> hiT/loT [N][K] (bf16 bits)
// ---------------------------------------------------------------------------
template <int KSH>
__global__ void tsplit(const float* __restrict__ W, ushort* __restrict__ hiT,
                       ushort* __restrict__ loT, int N) {
  const int K = 1 << KSH;
  int e = blockIdx.x * 256 + threadIdx.x;
  if (e >= N * K) return;
  int n = e >> KSH, k = e & (K - 1);
  float v = W[(size_t)k * N + n];
  ushort h = f2bf(v);
  hiT[e] = h;
  loT[e] = f2bf(v - bf2f(h));
}

// ---------------------------------------------------------------------------
// Split-precision bf16 MFMA GEMM: C = A(f32,[M][K]) * B(hi/lo bf16,[N][K]^T)
// 3 terms: Ahi*Bhi + Alo*Bhi + Ahi*Blo. BM=128, BN=128, BK=32, 256 thr =
// 4 waves (2x2), wave tile 64x64. A split in-kernel; B via global_load_lds
// with pre-swizzled source. LDS XOR-swizzled (see swz).
// ---------------------------------------------------------------------------
template <int KSH>
__global__ __launch_bounds__(256, 3) void gemm_split_mfma(
    const float* __restrict__ A, const ushort* __restrict__ Bhi_t,
    const ushort* __restrict__ Blo_t, float* __restrict__ C, int M, int N) {
  constexpr int K = 1 << KSH;
  __shared__ ushort Ahi[128 * 32], Alo[128 * 32];
  __shared__ ushort Bsh[128 * 32], Bsl[128 * 32];
  const int tid = threadIdx.x;
  const int lane = tid & 63;
  const int wid = tid >> 6;
  const int wm0 = (wid & 1) * 64;
  const int wn0 = (wid >> 1) * 64;
  const int bm0 = blockIdx.y * 128, bn0 = blockIdx.x * 128;
  const int r16 = lane & 15, g16 = lane >> 4;
  f32x4 acc[4][4] = {};

  // per-lane constants for B gload staging (2 instrs per wave per buffer)
  const int bcol0 = wid * 32 + (lane >> 2);        // i=0 column
  const int g_log0 = (lane & 3) ^ (bcol0 & 3);     // logical 8-elt chunk
  const int bcol1 = bcol0 + 16;                    // i=1 column
  const int g_log1 = (lane & 3) ^ (bcol1 & 3);

  for (int k0 = 0; k0 < K; k0 += 32) {
    __syncthreads();
    // --- B tiles: global_load_lds, source pre-swizzled, dest linear ---
    {
      size_t go0 = (((size_t)(bn0 + bcol0)) << KSH) + k0 + g_log0 * 8;
      size_t go1 = (((size_t)(bn0 + bcol1)) << KSH) + k0 + g_log1 * 8;
      ushort* lb0 = &Bsh[(wid * 32) * 32];          // wave-uniform
      ushort* lb1 = &Bsh[(wid * 32 + 16) * 32];
      ushort* lc0 = &Bsl[(wid * 32) * 32];
      ushort* lc1 = &Bsl[(wid * 32 + 16) * 32];
      gl16(&Bhi_t[go0], lb0);
      gl16(&Bhi_t[go1], lb1);
      gl16(&Blo_t[go0], lc0);
      gl16(&Blo_t[go1], lc1);
    }
    // --- A tile: load f32, split hi/lo, swizzled ds_write ---
#pragma unroll
    for (int u = 0; u < 4; u++) {
      int c = tid + u * 256;
      int row = c >> 3, kc = (c & 7) * 4;
      float4 v = *(const float4*)&A[(((size_t)(bm0 + row)) << KSH) + k0 + kc];
      ushort4 h, l;
      h.x = f2bf(v.x); l.x = f2bf(v.x - bf2f(h.x));
      h.y = f2bf(v.y); l.y = f2bf(v.y - bf2f(h.y));
      h.z = f2bf(v.z); l.z = f2bf(v.z - bf2f(h.z));
      h.w = f2bf(v.w); l.w = f2bf(v.w - bf2f(h.w));
      int o = swz(row, kc);
      *(ushort4*)&Ahi[o] = h;
      *(ushort4*)&Alo[o] = l;
    }
    __syncthreads();
    bf16x8 ah[4], al[4];
#pragma unroll
    for (int m = 0; m < 4; m++) {
      int o = swz(wm0 + m * 16 + r16, g16 * 8);
      ah[m] = *(const bf16x8*)&Ahi[o];
      al[m] = *(const bf16x8*)&Alo[o];
    }
#pragma unroll
    for (int n = 0; n < 4; n++) {
      int o = swz(wn0 + n * 16 + r16, g16 * 8);
      bf16x8 bh = *(const bf16x8*)&Bsh[o];
      bf16x8 bl = *(const bf16x8*)&Bsl[o];
#pragma unroll
      for (int m = 0; m < 4; m++) {
        acc[m][n] = __builtin_amdgcn_mfma_f32_16x16x32_bf16(ah[m], bh, acc[m][n], 0, 0, 0);
        acc[m][n] = __builtin_amdgcn_mfma_f32_16x16x32_bf16(al[m], bh, acc[m][n], 0, 0, 0);
        acc[m][n] = __builtin_amdgcn_mfma_f32_16x16x32_bf16(ah[m], bl, acc[m][n], 0, 0, 0);
      }
    }
  }
  const int crow = g16 * 4;
#pragma unroll
  for (int m = 0; m < 4; m++)
#pragma unroll
    for (int n = 0; n < 4; n++)
#pragma unroll
      for (int r = 0; r < 4; r++)
        C[(size_t)(bm0 + wm0 + m * 16 + crow + r) * N + bn0 + wn0 + n * 16 + r16] =
            acc[m][n][r];
}

// ---------------------------------------------------------------------------
// GCN aggregation, feature-split: grid (NB, 4), 256 threads. Each block does
// one graph x 128-feature chunk. CSR in LDS; 8 node-groups x 32 threads (f4).
// ---------------------------------------------------------------------------
__global__ __launch_bounds__(256) void gcn_agg(
    const float* __restrict__ h0, const int* __restrict__ ei,
    const float* __restrict__ b_gcn, float* __restrict__ h1) {
  const int g = blockIdx.x, fc0 = blockIdx.y * 128, tid = threadIdx.x;
  __shared__ int   deg[NN];
  __shared__ float sdinv[NN];
  __shared__ int   offs[NN + 1], fill[NN];
  __shared__ int   eSrc[NEL];
  __shared__ float eNrm[NEL];
  const int* src = ei + (size_t)g * 2 * NE;
  const int* dst = src + NE;

  if (tid < NN) deg[tid] = 1;
  __syncthreads();
  for (int e = tid; e < NE; e += 256) atomicAdd(&deg[dst[e]], 1);
  __syncthreads();
  if (tid < NN) sdinv[tid] = rsqrtf(fmaxf((float)deg[tid], 1e-12f));
  if (tid == 0) {
    int s = 0;
    for (int n = 0; n < NN; n++) { offs[n] = s; s += deg[n]; }
    offs[NN] = s;
  }
  __syncthreads();
  if (tid < NN) fill[tid] = offs[tid];
  __syncthreads();
  for (int e = tid; e < NE; e += 256) {
    int s = src[e], d = dst[e];
    int p = atomicAdd(&fill[d], 1);
    eSrc[p] = s;
    eNrm[p] = sdinv[s] * sdinv[d];
  }
  if (tid < NN) {
    int p = atomicAdd(&fill[tid], 1);
    eSrc[p] = tid;
    eNrm[p] = sdinv[tid] * sdinv[tid];
  }
  __syncthreads();

  const float* h0g = h0 + (size_t)g * NN * HG + fc0;
  float* h1g = h1 + (size_t)g * NN * HG + fc0;
  const int grp = tid >> 5, tf = tid & 31;
  float4 bias = *(const float4*)&b_gcn[fc0 + tf * 4];
  for (int n = grp; n < NN; n += 8) {
    float4 acc = bias;
    const int p1 = offs[n + 1];
    for (int p = offs[n]; p < p1; p++) {
      float nr = eNrm[p];
      float4 hv = *(const float4*)&h0g[(size_t)eSrc[p] * HG + tf * 4];
      acc.x = fmaf(hv.x, nr, acc.x);
      acc.y = fmaf(hv.y, nr, acc.y);
      acc.z = fmaf(hv.z, nr, acc.z);
      acc.w = fmaf(hv.w, nr, acc.w);
    }
    acc.x = fmaxf(acc.x, 0.f); acc.y = fmaxf(acc.y, 0.f);
    acc.z = fmaxf(acc.z, 0.f); acc.w = fmaxf(acc.w, 0.f);
    *(float4*)&h1g[(size_t)n * HG + tf * 4] = acc;
  }
}

__device__ inline unsigned fmap(float f) {
  unsigned b = __float_as_uint(f);
  return (b & 0x80000000u) ? ~b : (b | 0x80000000u);
}
__device__ inline float funmap(unsigned u) {
  return __uint_as_float((u & 0x80000000u) ? (u & 0x7fffffffu) : ~u);
}

// ---------------------------------------------------------------------------
// GAT attention: per-graph block, 256 threads. Computes alpha (segment
// softmax by dst), patch scores, and dumps dst-CSR (offs/src/alpha) to ws.
// ---------------------------------------------------------------------------
__global__ __launch_bounds__(256) void gat_alpha(
    const float* __restrict__ h2, const int* __restrict__ ei,
    const float* __restrict__ a_src, const float* __restrict__ a_dst,
    float* __restrict__ scores, int* __restrict__ csrO,
    int* __restrict__ csrS, float* __restrict__ csrA) {
  const int g = blockIdx.x, tid = threadIdx.x;
  __shared__ float    sAs[NN], sAd[NN];
  __shared__ unsigned mKey[NN];
  __shared__ float    sSum[NN], sAtt[NN];
  __shared__ int      sCnt[NN], degl[NN];
  __shared__ int      offs[NN + 1], fill[NN];
  __shared__ float    eV[NEL];
  __shared__ int      eS[NEL];
  __shared__ float    eA[NEL];
  const int* src = ei + (size_t)g * 2 * NE;
  const int* dst = src + NE;
  const float* h2g = h2 + (size_t)g * NN * DG;

  const int lane = tid & 63, wv = tid >> 6;
  for (int n = wv; n < NN; n += 4) {
    float4 hv  = *(const float4*)&h2g[(size_t)n * DG + lane * 4];
    float4 as4 = *(const float4*)&a_src[lane * 4];
    float4 ad4 = *(const float4*)&a_dst[lane * 4];
    float ps = hv.x * as4.x + hv.y * as4.y + hv.z * as4.z + hv.w * as4.w;
    float pd = hv.x * ad4.x + hv.y * ad4.y + hv.z * ad4.z + hv.w * ad4.w;
#pragma unroll
    for (int o = 32; o; o >>= 1) {
      ps += __shfl_down(ps, o);
      pd += __shfl_down(pd, o);
    }
    if (lane == 0) { sAs[n] = ps; sAd[n] = pd; }
  }
  if (tid < NN) {
    mKey[tid] = 0u; sSum[tid] = 0.f; sAtt[tid] = 0.f;
    sCnt[tid] = 0;  degl[tid] = 1;
  }
  __syncthreads();

  for (int i = tid; i < NEL; i += 256) {
    int s, d;
    if (i < NE) { s = src[i]; d = dst[i]; } else { s = d = i - NE; }
    float e = sAs[s] + sAd[d];
    e = (e > 0.f) ? e : NEG_SLOPE * e;
    eV[i] = e;
    atomicMax(&mKey[d], fmap(e));
    if (i < NE) atomicAdd(&degl[d], 1);
  }
  __syncthreads();

  for (int i = tid; i < NEL; i += 256) {
    int d = (i < NE) ? dst[i] : i - NE;
    float ex = expf(eV[i] - funmap(mKey[d]));
    eV[i] = ex;
    atomicAdd(&sSum[d], ex);
  }
  if (tid == 0) {
    int s = 0;
    for (int n = 0; n < NN; n++) { offs[n] = s; s += degl[n]; }
    offs[NN] = s;
  }
  __syncthreads();
  if (tid < NN) fill[tid] = offs[tid];
  __syncthreads();

  for (int i = tid; i < NEL; i += 256) {
    int s, d;
    if (i < NE) { s = src[i]; d = dst[i]; } else { s = d = i - NE; }
    float al = eV[i] / sSum[d];
    atomicAdd(&sAtt[s], al);
    atomicAdd(&sAtt[d], al);
    atomicAdd(&sCnt[s], 1);
    atomicAdd(&sCnt[d], 1);
    int p = atomicAdd(&fill[d], 1);
    eS[p] = s;
    eA[p] = al;
  }
  __syncthreads();

  if (tid < NN) scores[g * NN + tid] = sAtt[tid] / (float)sCnt[tid];
  if (tid <= NN) csrO[g * (NN + 1) + tid] = offs[tid];
  for (int i = tid; i < NEL; i += 256) {
    csrS[(size_t)g * NEL + i] = eS[i];
    csrA[(size_t)g * NEL + i] = eA[i];
  }
}

// ---------------------------------------------------------------------------
// GAT aggregation, feature-split: grid (NB, 2), 256 threads. One graph x
// 128-feature chunk per block; CSR staged from ws into LDS.
// ---------------------------------------------------------------------------
__global__ __launch_bounds__(256) void gat_agg(
    const float* __restrict__ h2, const int* __restrict__ csrO,
    const int* __restrict__ csrS, const float* __restrict__ csrA,
    const float* __restrict__ b_gat, float* __restrict__ out) {
  const int g = blockIdx.x, fc0 = blockIdx.y * 128, tid = threadIdx.x;
  __shared__ int   offs[NN + 1];
  __shared__ int   eS[NEL];
  __shared__ float eA[NEL];
  if (tid <= NN) offs[tid] = csrO[g * (NN + 1) + tid];
  for (int i = tid; i < NEL; i += 256) {
    eS[i] = csrS[(size_t)g * NEL + i];
    eA[i] = csrA[(size_t)g * NEL + i];
  }
  __syncthreads();

  const float* h2g = h2 + (size_t)g * NN * DG + fc0;
  float* outg = out + (size_t)g * NN * DG + fc0;
  const int grp = tid >> 5, tf = tid & 31;
  float4 bias = *(const float4*)&b_gat[fc0 + tf * 4];
  for (int n = grp; n < NN; n += 8) {
    float4 acc = bias;
    const int p1 = offs[n + 1];
    for (int p = offs[n]; p < p1; p++) {
      float al = eA[p];
      float4 hv = *(const float4*)&h2g[(size_t)eS[p] * DG + tf * 4];
      acc.x = fmaf(hv.x, al, acc.x);
      acc.y = fmaf(hv.y, al, acc.y);
      acc.z = fmaf(hv.z, al, acc.z);
      acc.w = fmaf(hv.w, al, acc.w);
    }
    *(float4*)&outg[(size_t)n * DG + tf * 4] = acc;
  }
}

// ---------------------------------------------------------------------------
// Radix-select top-50 of 25600 scores (single block, 1024 threads).
// ---------------------------------------------------------------------------
__global__ __launch_bounds__(1024) void topk_radix(
    const float* __restrict__ scores, int* __restrict__ topk) {
  const int tid = threadIdx.x;
  unsigned key[25];
#pragma unroll
  for (int u = 0; u < 25; u++) key[u] = fmap(scores[tid + u * 1024]);

  __shared__ unsigned hist[16][256];
  __shared__ unsigned total[256];
  __shared__ unsigned sPref;
  __shared__ int sNeed;
  const int wv = tid >> 6;
  unsigned pref = 0;
  int plen = 0, need = KTOP;
  for (int pass = 0; pass < 4; pass++) {
    const int shift = 24 - 8 * pass;
    for (int i = tid; i < 16 * 256; i += 1024) ((unsigned*)hist)[i] = 0;
    __syncthreads();
#pragma unroll
    for (int u = 0; u < 25; u++) {
      unsigned k = key[u];
      bool ok = (plen == 0) || ((k >> (32 - plen)) == (pref >> (32 - plen)));
      if (ok) atomicAdd(&hist[wv][(k >> shift) & 255], 1u);
    }
    __syncthreads();
    if (tid < 256) {
      unsigned s = 0;
      for (int w = 0; w < 16; w++) s += hist[w][tid];
      total[tid] = s;
    }
    __syncthreads();
    if (tid == 0) {
      unsigned cum = 0;
      int b = 255;
      for (; b > 0; b--) {
        cum += total[b];
        if ((int)cum >= need) break;
      }
      if ((int)cum < need) cum += total[0];
      sPref = pref | ((unsigned)b << shift);
      sNeed = need - (int)(cum - total[b]);
    }
    __syncthreads();
    pref = sPref;
    need = sNeed;
    plen += 8;
    __syncthreads();
  }

  const unsigned thr = pref;
  __shared__ int nGt;
  __shared__ unsigned long long cand[64];
  __shared__ int eqMin;
  if (tid == 0) nGt = 0;
  __syncthreads();
  unsigned eqmask = 0;
#pragma unroll
  for (int u = 0; u < 25; u++) {
    unsigned k = key[u];
    if (k > thr) {
      int p = atomicAdd(&nGt, 1);
      cand[p] = ((unsigned long long)k << 32) | (unsigned)(~(tid + u * 1024));
    } else if (k == thr) {
      eqmask |= 1u << u;
    }
  }
  __syncthreads();
  const int base = nGt;
  for (int r = 0; r < need; r++) {
    if (tid == 0) eqMin = 0x7fffffff;
    __syncthreads();
    int mymin = 0x7fffffff;
    unsigned mm = eqmask;
    while (mm) {
      int u = __ffs(mm) - 1;
      mm &= mm - 1;
      int idx = tid + u * 1024;
      if (idx < mymin) mymin = idx;
    }
#pragma unroll
    for (int o = 32; o; o >>= 1) {
      int ot = __shfl_down(mymin, o);
      if (ot < mymin) mymin = ot;
    }
    if ((tid & 63) == 0 && mymin != 0x7fffffff) atomicMin(&eqMin, mymin);
    __syncthreads();
    int sel = eqMin;
    if (tid == 0) topk[base + r] = sel;
    if ((sel & 1023) == tid) eqmask &= ~(1u << (sel >> 10));
    __syncthreads();
  }
  if (tid < 64) {
    unsigned long long c = (tid < base) ? cand[tid] : 0ull;
    for (int r = 0; r < base; r++) {
      unsigned long long m = c;
#pragma unroll
      for (int o = 32; o; o >>= 1) {
        unsigned long long t2 = __shfl_down(m, o);
        if (t2 > m) m = t2;
      }
      m = __shfl(m, 0);
      if (tid == 0) topk[r] = (int)(~(unsigned)m);
      if (c == m) c = 0ull;
    }
  }
}

// ---------------------------------------------------------------------------
// Project the 50 selected rows: out[i,:] = gnn[idx[i],:] @ W_proj + b_proj
// ---------------------------------------------------------------------------
__global__ __launch_bounds__(256) void proj_kernel(
    const float* __restrict__ gnn, const int* __restrict__ topk,
    const float* __restrict__ Wp, const float* __restrict__ bp,
    float* __restrict__ outp) {
  const int bi = blockIdx.x >> 2;
  const int c0 = (blockIdx.x & 3) * 256;
  const int tid = threadIdx.x;
  __shared__ float row[DG];
  const int node = topk[bi];
  row[tid] = gnn[(size_t)node * DG + tid];
  __syncthreads();
  float acc = 0.f;
  for (int k = 0; k < DG; k++)
    acc = fmaf(row[k], Wp[(size_t)k * PO + c0 + tid], acc);
  outp[(size_t)bi * PO + c0 + tid] = acc + bp[c0 + tid];
}

// ---------------------------------------------------------------------------
extern "C" void kernel_launch(void* const* d_in, const int* in_sizes, int n_in,
                              void* d_out, int out_size, void* d_ws,
                              size_t ws_size, hipStream_t stream) {
  const float* x      = (const float*)d_in[0];
  const int*   ei     = (const int*)d_in[1];
  const float* W_gcn  = (const float*)d_in[2];
  const float* b_gcn  = (const float*)d_in[3];
  const float* W_gat  = (const float*)d_in[4];
  const float* b_gat  = (const float*)d_in[5];
  const float* a_src  = (const float*)d_in[6];
  const float* a_dst  = (const float*)d_in[7];
  const float* W_proj = (const float*)d_in[8];
  const float* b_proj = (const float*)d_in[9];
  float* outp = (float*)d_out;

  // workspace (~113 MB)
  char* ws = (char*)d_ws;
  float*  h0       = (float*)ws;                    // [25600][512] f32
  float*  h2       = (float*)ws;                    // [25600][256] (h0 dead)
  float*  gnn      = (float*)(ws + 26214400);       // [25600][256]
  float*  h1       = (float*)(ws + 52428800);       // [25600][512]
  char*   wsc      = ws + 104857600;
  ushort* WgcnT_hi = (ushort*)(wsc);
  ushort* WgcnT_lo = (ushort*)(wsc + 2097152);
  ushort* WgatT_hi = (ushort*)(wsc + 4194304);
  ushort* WgatT_lo = (ushort*)(wsc + 4456448);
  float*  scores   = (float*)(wsc + 4718592);
  int*    topk     = (int*)(wsc + 4820992);
  int*    csrO     = (int*)(wsc + 4823040);         // 256*101 ints
  int*    csrS     = (int*)(wsc + 4926464);         // 256*1700 ints
  float*  csrA     = (float*)(wsc + 6667264);       // 256*1700 f32

  const int M = NB * NN;  // 25600

  tsplit<11><<<(HG * FIN + 255) / 256, 256, 0, stream>>>(W_gcn, WgcnT_hi,
                                                         WgcnT_lo, HG);
  tsplit<9><<<(DG * HG + 255) / 256, 256, 0, stream>>>(W_gat, WgatT_hi,
                                                       WgatT_lo, DG);
  // H0 = x @ W_gcn   [25600,2048]x[2048,512]
  gemm_split_mfma<11><<<dim3(HG / 128, M / 128), 256, 0, stream>>>(
      x, WgcnT_hi, WgcnT_lo, h0, M, HG);
  // H1 = relu(norm-agg(H0) + b_gcn)   (feature-split, 1024 blocks)
  gcn_agg<<<dim3(NB, 4), 256, 0, stream>>>(h0, ei, b_gcn, h1);
  // H2 = H1 @ W_gat  [25600,512]x[512,256]
  gemm_split_mfma<9><<<dim3(DG / 128, M / 128), 256, 0, stream>>>(
      h1, WgatT_hi, WgatT_lo, h2, M, DG);
  // GAT attention -> alpha CSR + scores
  gat_alpha<<<NB, 256, 0, stream>>>(h2, ei, a_src, a_dst, scores, csrO, csrS,
                                    csrA);
  // GAT aggregation (feature-split, 512 blocks)
  gat_agg<<<dim3(NB, 2), 256, 0, stream>>>(h2, csrO, csrS, csrA, b_gat, gnn);
  // top-50
  topk_radix<<<1, 1024, 0, stream>>>(scores, topk);
  // project selected rows
  proj_kernel<<<KTOP * 4, 256, 0, stream>>>(gnn, topk, W_proj, b_proj, outp);
}

// Round 5
// 714.698 us; speedup vs baseline: 1.1479x; 1.1479x over previous
//
#include <hip/hip_runtime.h>
#include <hip/hip_bf16.h>
#include <stdint.h>

#define NB      256
#define NN      100
#define NE      1600
#define NEL     1700
#define FIN     2048
#define HG      512
#define DG      256
#define PO      1024
#define KTOP    50
#define NEG_SLOPE 0.2f

typedef __attribute__((ext_vector_type(8))) short bf16x8;
typedef __attribute__((ext_vector_type(4))) float f32x4;
typedef unsigned int u32;

__device__ inline ushort f2bf(float x) {
  unsigned u = __float_as_uint(x);
  return (ushort)((u + 0x7fffu + ((u >> 16) & 1u)) >> 16);
}
__device__ inline float bf2f(ushort b) {
  return __uint_as_float((unsigned)b << 16);
}

// global -> LDS direct copy, 16B/lane. LDS dest wave-uniform base (HW adds
// lane*16); global src per-lane.
__device__ inline void gl16(const void* g, void* l) {
  __builtin_amdgcn_global_load_lds(
      (const __attribute__((address_space(1))) u32*)g,
      (__attribute__((address_space(3))) u32*)l, 16, 0, 0);
}

// LDS swizzle: 64B rows of 4x16B chunks; stored chunk = logical ^ ((row>>1)&3).
// Frag-read (16 consecutive rows, fixed logical chunk) then spreads over all
// 8 mod-128 slots -> 2-way (free). ushort index:
__device__ inline int swz(int row, int kc) {
  return row * 32 + ((((kc >> 3) ^ ((row >> 1) & 3)) << 3) | (kc & 7));
}

// ---------------------------------------------------------------------------
// Fused transpose+split of both weights: W[K][N] -> hiT/loT [N][K] bf16 bits
// ---------------------------------------------------------------------------
__global__ void tsplit_both(const float* __restrict__ Wg,
                            ushort* __restrict__ gh, ushort* __restrict__ gl_,
                            const float* __restrict__ Wa,
                            ushort* __restrict__ ah, ushort* __restrict__ al) {
  int e = blockIdx.x * 256 + threadIdx.x;
  if (e < HG * FIN) {                    // W_gcn [2048][512] -> [512][2048]
    int n = e >> 11, k = e & 2047;
    float v = Wg[(size_t)k * HG + n];
    ushort h = f2bf(v);
    gh[e] = h;
    gl_[e] = f2bf(v - bf2f(h));
  } else {
    int e2 = e - HG * FIN;
    if (e2 < DG * HG) {                  // W_gat [512][256] -> [256][512]
      int n = e2 >> 9, k = e2 & 511;
      float v = Wa[(size_t)k * DG + n];
      ushort h = f2bf(v);
      ah[e2] = h;
      al[e2] = f2bf(v - bf2f(h));
    }
  }
}

// ---------------------------------------------------------------------------
// Split-precision bf16 MFMA GEMM: C = A(f32,[M][K]) * B(hi/lo bf16,[N][K]^T)
// 3 terms: Ahi*Bhi + Alo*Bhi + Ahi*Blo. BM=128, BN=256, BK=32, 256 thr =
// 4 waves (2x2), wave tile 64x128. B staged via global_load_lds with
// pre-swizzled source; A split in-kernel with swizzled ds_write.
// ---------------------------------------------------------------------------
template <int KSH>
__global__ __launch_bounds__(256, 2) void gemm_split_mfma(
    const float* __restrict__ A, const ushort* __restrict__ Bhi_t,
    const ushort* __restrict__ Blo_t, float* __restrict__ C, int M, int N) {
  constexpr int K = 1 << KSH;
  __shared__ ushort Ahi[128 * 32], Alo[128 * 32];
  __shared__ ushort Bsh[256 * 32], Bsl[256 * 32];
  const int tid = threadIdx.x;
  const int lane = tid & 63;
  const int wid = tid >> 6;
  const int wm0 = (wid & 1) * 64;
  const int wn0 = (wid >> 1) * 128;
  const int bm0 = blockIdx.y * 128, bn0 = blockIdx.x * 256;
  const int r16 = lane & 15, g16 = lane >> 4;
  f32x4 acc[4][8] = {};

  for (int k0 = 0; k0 < K; k0 += 32) {
    __syncthreads();
    // --- B tiles via glds: 4 instrs/buffer/wave, 16 cols (1KB) each ---
#pragma unroll
    for (int i = 0; i < 4; i++) {
      const int colb = wid * 64 + i * 16;              // wave-uniform
      const int col = colb + (lane >> 2);
      const int rot = (col >> 1) & 3;
      size_t go = (((size_t)(bn0 + col)) << KSH) + k0 + (((lane & 3) ^ rot) << 3);
      gl16(&Bhi_t[go], &Bsh[colb * 32]);
      gl16(&Blo_t[go], &Bsl[colb * 32]);
    }
    // --- A tile: f32 load, hi/lo split, swizzled ds_write ---
#pragma unroll
    for (int u = 0; u < 4; u++) {
      int c = tid + u * 256;
      int row = c >> 3, kc = (c & 7) * 4;
      float4 v = *(const float4*)&A[(((size_t)(bm0 + row)) << KSH) + k0 + kc];
      ushort4 h, l;
      h.x = f2bf(v.x); l.x = f2bf(v.x - bf2f(h.x));
      h.y = f2bf(v.y); l.y = f2bf(v.y - bf2f(h.y));
      h.z = f2bf(v.z); l.z = f2bf(v.z - bf2f(h.z));
      h.w = f2bf(v.w); l.w = f2bf(v.w - bf2f(h.w));
      int o = swz(row, kc);
      *(ushort4*)&Ahi[o] = h;
      *(ushort4*)&Alo[o] = l;
    }
    __syncthreads();
    bf16x8 ahf[4], alf[4];
#pragma unroll
    for (int m = 0; m < 4; m++) {
      int o = swz(wm0 + m * 16 + r16, g16 * 8);
      ahf[m] = *(const bf16x8*)&Ahi[o];
      alf[m] = *(const bf16x8*)&Alo[o];
    }
#pragma unroll
    for (int n = 0; n < 8; n++) {
      int o = swz(wn0 + n * 16 + r16, g16 * 8);
      bf16x8 bh = *(const bf16x8*)&Bsh[o];
      bf16x8 bl = *(const bf16x8*)&Bsl[o];
#pragma unroll
      for (int m = 0; m < 4; m++) {
        acc[m][n] = __builtin_amdgcn_mfma_f32_16x16x32_bf16(ahf[m], bh, acc[m][n], 0, 0, 0);
        acc[m][n] = __builtin_amdgcn_mfma_f32_16x16x32_bf16(alf[m], bh, acc[m][n], 0, 0, 0);
        acc[m][n] = __builtin_amdgcn_mfma_f32_16x16x32_bf16(ahf[m], bl, acc[m][n], 0, 0, 0);
      }
    }
  }
  const int crow = g16 * 4;
#pragma unroll
  for (int m = 0; m < 4; m++)
#pragma unroll
    for (int n = 0; n < 8; n++)
#pragma unroll
      for (int r = 0; r < 4; r++)
        C[(size_t)(bm0 + wm0 + m * 16 + crow + r) * N + bn0 + wn0 + n * 16 + r16] =
            acc[m][n][r];
}

// ---------------------------------------------------------------------------
// GCN aggregation, feature-split: grid (NB, 4), 256 threads.
// ---------------------------------------------------------------------------
__global__ __launch_bounds__(256) void gcn_agg(
    const float* __restrict__ h0, const int* __restrict__ ei,
    const float* __restrict__ b_gcn, float* __restrict__ h1) {
  const int g = blockIdx.x, fc0 = blockIdx.y * 128, tid = threadIdx.x;
  __shared__ int   deg[NN];
  __shared__ float sdinv[NN];
  __shared__ int   offs[NN + 1], fill[NN];
  __shared__ int   eSrc[NEL];
  __shared__ float eNrm[NEL];
  const int* src = ei + (size_t)g * 2 * NE;
  const int* dst = src + NE;

  if (tid < NN) deg[tid] = 1;
  __syncthreads();
  for (int e = tid; e < NE; e += 256) atomicAdd(&deg[dst[e]], 1);
  __syncthreads();
  if (tid < NN) sdinv[tid] = rsqrtf(fmaxf((float)deg[tid], 1e-12f));
  if (tid == 0) {
    int s = 0;
    for (int n = 0; n < NN; n++) { offs[n] = s; s += deg[n]; }
    offs[NN] = s;
  }
  __syncthreads();
  if (tid < NN) fill[tid] = offs[tid];
  __syncthreads();
  for (int e = tid; e < NE; e += 256) {
    int s = src[e], d = dst[e];
    int p = atomicAdd(&fill[d], 1);
    eSrc[p] = s;
    eNrm[p] = sdinv[s] * sdinv[d];
  }
  if (tid < NN) {
    int p = atomicAdd(&fill[tid], 1);
    eSrc[p] = tid;
    eNrm[p] = sdinv[tid] * sdinv[tid];
  }
  __syncthreads();

  const float* h0g = h0 + (size_t)g * NN * HG + fc0;
  float* h1g = h1 + (size_t)g * NN * HG + fc0;
  const int grp = tid >> 5, tf = tid & 31;
  float4 bias = *(const float4*)&b_gcn[fc0 + tf * 4];
  for (int n = grp; n < NN; n += 8) {
    float4 acc = bias;
    const int p1 = offs[n + 1];
    for (int p = offs[n]; p < p1; p++) {
      float nr = eNrm[p];
      float4 hv = *(const float4*)&h0g[(size_t)eSrc[p] * HG + tf * 4];
      acc.x = fmaf(hv.x, nr, acc.x);
      acc.y = fmaf(hv.y, nr, acc.y);
      acc.z = fmaf(hv.z, nr, acc.z);
      acc.w = fmaf(hv.w, nr, acc.w);
    }
    acc.x = fmaxf(acc.x, 0.f); acc.y = fmaxf(acc.y, 0.f);
    acc.z = fmaxf(acc.z, 0.f); acc.w = fmaxf(acc.w, 0.f);
    *(float4*)&h1g[(size_t)n * HG + tf * 4] = acc;
  }
}

__device__ inline unsigned fmap(float f) {
  unsigned b = __float_as_uint(f);
  return (b & 0x80000000u) ? ~b : (b | 0x80000000u);
}
__device__ inline float funmap(unsigned u) {
  return __uint_as_float((u & 0x80000000u) ? (u & 0x7fffffffu) : ~u);
}

// ---------------------------------------------------------------------------
// GAT attention: per-graph block, 256 threads -> alpha CSR + patch scores
// ---------------------------------------------------------------------------
__global__ __launch_bounds__(256) void gat_alpha(
    const float* __restrict__ h2, const int* __restrict__ ei,
    const float* __restrict__ a_src, const float* __restrict__ a_dst,
    float* __restrict__ scores, int* __restrict__ csrO,
    int* __restrict__ csrS, float* __restrict__ csrA) {
  const int g = blockIdx.x, tid = threadIdx.x;
  __shared__ float    sAs[NN], sAd[NN];
  __shared__ unsigned mKey[NN];
  __shared__ float    sSum[NN], sAtt[NN];
  __shared__ int      sCnt[NN], degl[NN];
  __shared__ int      offs[NN + 1], fill[NN];
  __shared__ float    eV[NEL];
  __shared__ int      eS[NEL];
  __shared__ float    eA[NEL];
  const int* src = ei + (size_t)g * 2 * NE;
  const int* dst = src + NE;
  const float* h2g = h2 + (size_t)g * NN * DG;

  const int lane = tid & 63, wv = tid >> 6;
  for (int n = wv; n < NN; n += 4) {
    float4 hv  = *(const float4*)&h2g[(size_t)n * DG + lane * 4];
    float4 as4 = *(const float4*)&a_src[lane * 4];
    float4 ad4 = *(const float4*)&a_dst[lane * 4];
    float ps = hv.x * as4.x + hv.y * as4.y + hv.z * as4.z + hv.w * as4.w;
    float pd = hv.x * ad4.x + hv.y * ad4.y + hv.z * ad4.z + hv.w * ad4.w;
#pragma unroll
    for (int o = 32; o; o >>= 1) {
      ps += __shfl_down(ps, o);
      pd += __shfl_down(pd, o);
    }
    if (lane == 0) { sAs[n] = ps; sAd[n] = pd; }
  }
  if (tid < NN) {
    mKey[tid] = 0u; sSum[tid] = 0.f; sAtt[tid] = 0.f;
    sCnt[tid] = 0;  degl[tid] = 1;
  }
  __syncthreads();

  for (int i = tid; i < NEL; i += 256) {
    int s, d;
    if (i < NE) { s = src[i]; d = dst[i]; } else { s = d = i - NE; }
    float e = sAs[s] + sAd[d];
    e = (e > 0.f) ? e : NEG_SLOPE * e;
    eV[i] = e;
    atomicMax(&mKey[d], fmap(e));
    if (i < NE) atomicAdd(&degl[d], 1);
  }
  __syncthreads();

  for (int i = tid; i < NEL; i += 256) {
    int d = (i < NE) ? dst[i] : i - NE;
    float ex = expf(eV[i] - funmap(mKey[d]));
    eV[i] = ex;
    atomicAdd(&sSum[d], ex);
  }
  if (tid == 0) {
    int s = 0;
    for (int n = 0; n < NN; n++) { offs[n] = s; s += degl[n]; }
    offs[NN] = s;
  }
  __syncthreads();
  if (tid < NN) fill[tid] = offs[tid];
  __syncthreads();

  for (int i = tid; i < NEL; i += 256) {
    int s, d;
    if (i < NE) { s = src[i]; d = dst[i]; } else { s = d = i - NE; }
    float al = eV[i] / sSum[d];
    atomicAdd(&sAtt[s], al);
    atomicAdd(&sAtt[d], al);
    atomicAdd(&sCnt[s], 1);
    atomicAdd(&sCnt[d], 1);
    int p = atomicAdd(&fill[d], 1);
    eS[p] = s;
    eA[p] = al;
  }
  __syncthreads();

  if (tid < NN) scores[g * NN + tid] = sAtt[tid] / (float)sCnt[tid];
  if (tid <= NN) csrO[g * (NN + 1) + tid] = offs[tid];
  for (int i = tid; i < NEL; i += 256) {
    csrS[(size_t)g * NEL + i] = eS[i];
    csrA[(size_t)g * NEL + i] = eA[i];
  }
}

// ---------------------------------------------------------------------------
// GAT aggregation, feature-split: grid (NB, 2), 256 threads.
// ---------------------------------------------------------------------------
__global__ __launch_bounds__(256) void gat_agg(
    const float* __restrict__ h2, const int* __restrict__ csrO,
    const int* __restrict__ csrS, const float* __restrict__ csrA,
    const float* __restrict__ b_gat, float* __restrict__ out) {
  const int g = blockIdx.x, fc0 = blockIdx.y * 128, tid = threadIdx.x;
  __shared__ int   offs[NN + 1];
  __shared__ int   eS[NEL];
  __shared__ float eA[NEL];
  if (tid <= NN) offs[tid] = csrO[g * (NN + 1) + tid];
  for (int i = tid; i < NEL; i += 256) {
    eS[i] = csrS[(size_t)g * NEL + i];
    eA[i] = csrA[(size_t)g * NEL + i];
  }
  __syncthreads();

  const float* h2g = h2 + (size_t)g * NN * DG + fc0;
  float* outg = out + (size_t)g * NN * DG + fc0;
  const int grp = tid >> 5, tf = tid & 31;
  float4 bias = *(const float4*)&b_gat[fc0 + tf * 4];
  for (int n = grp; n < NN; n += 8) {
    float4 acc = bias;
    const int p1 = offs[n + 1];
    for (int p = offs[n]; p < p1; p++) {
      float al = eA[p];
      float4 hv = *(const float4*)&h2g[(size_t)eS[p] * DG + tf * 4];
      acc.x = fmaf(hv.x, al, acc.x);
      acc.y = fmaf(hv.y, al, acc.y);
      acc.z = fmaf(hv.z, al, acc.z);
      acc.w = fmaf(hv.w, al, acc.w);
    }
    *(float4*)&outg[(size_t)n * DG + tf * 4] = acc;
  }
}

// ---------------------------------------------------------------------------
// Radix-select top-50 of 25600 (1 block, 1024 thr). Parallel suffix scan.
// ---------------------------------------------------------------------------
__global__ __launch_bounds__(1024) void topk_radix(
    const float* __restrict__ scores, int* __restrict__ topk) {
  const int tid = threadIdx.x;
  unsigned key[25];
#pragma unroll
  for (int u = 0; u < 25; u++) key[u] = fmap(scores[tid + u * 1024]);

  __shared__ unsigned hist[16][256];
  __shared__ unsigned total[256], suff[257];
  __shared__ unsigned sPref;
  __shared__ int sNeed;
  const int wv = tid >> 6;
  unsigned pref = 0;
  int plen = 0, need = KTOP;
  for (int pass = 0; pass < 4; pass++) {
    const int shift = 24 - 8 * pass;
    for (int i = tid; i < 16 * 256; i += 1024) ((unsigned*)hist)[i] = 0;
    __syncthreads();
#pragma unroll
    for (int u = 0; u < 25; u++) {
      unsigned k = key[u];
      bool ok = (plen == 0) || ((k >> (32 - plen)) == (pref >> (32 - plen)));
      if (ok) atomicAdd(&hist[wv][(k >> shift) & 255], 1u);
    }
    __syncthreads();
    if (tid < 256) {
      unsigned s = 0;
#pragma unroll
      for (int w = 0; w < 16; w++) s += hist[w][tid];
      total[tid] = s;
      suff[tid] = s;
      if (tid == 0) suff[256] = 0;
    }
    __syncthreads();
    // inclusive suffix sum over 256 buckets
    for (int st = 1; st < 256; st <<= 1) {
      unsigned v = 0;
      if (tid < 256) v = suff[tid] + ((tid + st < 256) ? suff[tid + st] : 0u);
      __syncthreads();
      if (tid < 256) suff[tid] = v;
      __syncthreads();
    }
    if (tid < 256) {
      unsigned s1 = suff[tid + 1];
      if (suff[tid] >= (unsigned)need && s1 < (unsigned)need) {
        sPref = pref | ((unsigned)tid << shift);
        sNeed = need - (int)s1;
      }
    }
    __syncthreads();
    pref = sPref;
    need = sNeed;
    plen += 8;
    __syncthreads();
  }

  const unsigned thr = pref;
  __shared__ int nGt;
  __shared__ unsigned long long cand[64];
  __shared__ int eqMin;
  if (tid == 0) nGt = 0;
  __syncthreads();
  unsigned eqmask = 0;
#pragma unroll
  for (int u = 0; u < 25; u++) {
    unsigned k = key[u];
    if (k > thr) {
      int p = atomicAdd(&nGt, 1);
      cand[p] = ((unsigned long long)k << 32) | (unsigned)(~(tid + u * 1024));
    } else if (k == thr) {
      eqmask |= 1u << u;
    }
  }
  __syncthreads();
  const int base = nGt;
  for (int r = 0; r < need; r++) {
    if (tid == 0) eqMin = 0x7fffffff;
    __syncthreads();
    int mymin = 0x7fffffff;
    unsigned mm = eqmask;
    while (mm) {
      int u = __ffs(mm) - 1;
      mm &= mm - 1;
      int idx = tid + u * 1024;
      if (idx < mymin) mymin = idx;
    }
#pragma unroll
    for (int o = 32; o; o >>= 1) {
      int ot = __shfl_down(mymin, o);
      if (ot < mymin) mymin = ot;
    }
    if ((tid & 63) == 0 && mymin != 0x7fffffff) atomicMin(&eqMin, mymin);
    __syncthreads();
    int sel = eqMin;
    if (tid == 0) topk[base + r] = sel;
    if ((sel & 1023) == tid) eqmask &= ~(1u << (sel >> 10));
    __syncthreads();
  }
  if (tid < 64) {
    unsigned long long c = (tid < base) ? cand[tid] : 0ull;
    for (int r = 0; r < base; r++) {
      unsigned long long m = c;
#pragma unroll
      for (int o = 32; o; o >>= 1) {
        unsigned long long t2 = __shfl_down(m, o);
        if (t2 > m) m = t2;
      }
      m = __shfl(m, 0);
      if (tid == 0) topk[r] = (int)(~(unsigned)m);
      if (c == m) c = 0ull;
    }
  }
}

// ---------------------------------------------------------------------------
// Project the 50 selected rows: out[i,:] = gnn[idx[i],:] @ W_proj + b_proj
// ---------------------------------------------------------------------------
__global__ __launch_bounds__(256) void proj_kernel(
    const float* __restrict__ gnn, const int* __restrict__ topk,
    const float* __restrict__ Wp, const float* __restrict__ bp,
    float* __restrict__ outp) {
  const int bi = blockIdx.x >> 2;
  const int c0 = (blockIdx.x & 3) * 256;
  const int tid = threadIdx.x;
  __shared__ float row[DG];
  const int node = topk[bi];
  row[tid] = gnn[(size_t)node * DG + tid];
  __syncthreads();
  float acc = 0.f;
#pragma unroll 8
  for (int k = 0; k < DG; k++)
    acc = fmaf(row[k], Wp[(size_t)k * PO + c0 + tid], acc);
  outp[(size_t)bi * PO + c0 + tid] = acc + bp[c0 + tid];
}

// ---------------------------------------------------------------------------
extern "C" void kernel_launch(void* const* d_in, const int* in_sizes, int n_in,
                              void* d_out, int out_size, void* d_ws,
                              size_t ws_size, hipStream_t stream) {
  const float* x      = (const float*)d_in[0];
  const int*   ei     = (const int*)d_in[1];
  const float* W_gcn  = (const float*)d_in[2];
  const float* b_gcn  = (const float*)d_in[3];
  const float* W_gat  = (const float*)d_in[4];
  const float* b_gat  = (const float*)d_in[5];
  const float* a_src  = (const float*)d_in[6];
  const float* a_dst  = (const float*)d_in[7];
  const float* W_proj = (const float*)d_in[8];
  const float* b_proj = (const float*)d_in[9];
  float* outp = (float*)d_out;

  char* ws = (char*)d_ws;
  float*  h0       = (float*)ws;                    // [25600][512] f32
  float*  h2       = (float*)ws;                    // [25600][256] (h0 dead)
  float*  gnn      = (float*)(ws + 26214400);       // [25600][256]
  float*  h1       = (float*)(ws + 52428800);       // [25600][512]
  char*   wsc      = ws + 104857600;
  ushort* WgcnT_hi = (ushort*)(wsc);
  ushort* WgcnT_lo = (ushort*)(wsc + 2097152);
  ushort* WgatT_hi = (ushort*)(wsc + 4194304);
  ushort* WgatT_lo = (ushort*)(wsc + 4456448);
  float*  scores   = (float*)(wsc + 4718592);
  int*    topk     = (int*)(wsc + 4820992);
  int*    csrO     = (int*)(wsc + 4823040);
  int*    csrS     = (int*)(wsc + 4926464);
  float*  csrA     = (float*)(wsc + 6667264);

  const int M = NB * NN;  // 25600

  tsplit_both<<<(HG * FIN + DG * HG + 255) / 256, 256, 0, stream>>>(
      W_gcn, WgcnT_hi, WgcnT_lo, W_gat, WgatT_hi, WgatT_lo);
  // H0 = x @ W_gcn   [25600,2048]x[2048,512]
  gemm_split_mfma<11><<<dim3(HG / 256, M / 128), 256, 0, stream>>>(
      x, WgcnT_hi, WgcnT_lo, h0, M, HG);
  // H1 = relu(norm-agg(H0) + b_gcn)
  gcn_agg<<<dim3(NB, 4), 256, 0, stream>>>(h0, ei, b_gcn, h1);
  // H2 = H1 @ W_gat  [25600,512]x[512,256]
  gemm_split_mfma<9><<<dim3(DG / 256, M / 128), 256, 0, stream>>>(
      h1, WgatT_hi, WgatT_lo, h2, M, DG);
  // GAT attention -> alpha CSR + scores
  gat_alpha<<<NB, 256, 0, stream>>>(h2, ei, a_src, a_dst, scores, csrO, csrS,
                                    csrA);
  // GAT aggregation
  gat_agg<<<dim3(NB, 2), 256, 0, stream>>>(h2, csrO, csrS, csrA, b_gat, gnn);
  // top-50
  topk_radix<<<1, 1024, 0, stream>>>(scores, topk);
  // project selected rows
  proj_kernel<<<KTOP * 4, 256, 0, stream>>>(gnn, topk, W_proj, b_proj, outp);
}

// Round 6
// 648.479 us; speedup vs baseline: 1.2651x; 1.1021x over previous
//
#include <hip/hip_runtime.h>
#include <hip/hip_bf16.h>
#include <stdint.h>

#define NB      256
#define NN      100
#define NE      1600
#define NEL     1700
#define FIN     2048
#define HG      512
#define DG      256
#define PO      1024
#define KTOP    50
#define NEG_SLOPE 0.2f

typedef __attribute__((ext_vector_type(8))) short bf16x8;
typedef __attribute__((ext_vector_type(8))) unsigned short u16x8;
typedef __attribute__((ext_vector_type(4))) float f32x4;
typedef unsigned int u32;

__device__ inline ushort f2bf(float x) {
  unsigned u = __float_as_uint(x);
  return (ushort)((u + 0x7fffu + ((u >> 16) & 1u)) >> 16);
}
__device__ inline float bf2f(ushort b) {
  return __uint_as_float((unsigned)b << 16);
}

// global -> LDS direct copy, 16B/lane (wave-uniform LDS base, per-lane src)
__device__ inline void gl16(const void* g, void* l) {
  __builtin_amdgcn_global_load_lds(
      (const __attribute__((address_space(1))) u32*)g,
      (__attribute__((address_space(3))) u32*)l, 16, 0, 0);
}

// LDS swizzle: rows of 32 ushorts (64B) = 4 x 16B chunks; stored chunk =
// logical ^ ((row>>1)&3). Proven zero-conflict in r5.
__device__ inline int swz(int row, int kc) {
  return row * 32 + ((((kc >> 3) ^ ((row >> 1) & 3)) << 3) | (kc & 7));
}

__device__ inline void split8(float4 a, float4 b, u16x8& h, u16x8& l) {
  float v[8] = {a.x, a.y, a.z, a.w, b.x, b.y, b.z, b.w};
#pragma unroll
  for (int i = 0; i < 8; i++) {
    ushort hh = f2bf(v[i]);
    h[i] = hh;
    l[i] = f2bf(v[i] - bf2f(hh));
  }
}

// ---------------------------------------------------------------------------
// Fused transpose+split of both weights: W[K][N] -> hiT/loT [N][K] bf16 bits
// ---------------------------------------------------------------------------
__global__ void tsplit_both(const float* __restrict__ Wg,
                            ushort* __restrict__ gh, ushort* __restrict__ gl_,
                            const float* __restrict__ Wa,
                            ushort* __restrict__ ah, ushort* __restrict__ al) {
  int e = blockIdx.x * 256 + threadIdx.x;
  if (e < HG * FIN) {                    // W_gcn [2048][512] -> [512][2048]
    int n = e >> 11, k = e & 2047;
    float v = Wg[(size_t)k * HG + n];
    ushort h = f2bf(v);
    gh[e] = h;
    gl_[e] = f2bf(v - bf2f(h));
  } else {
    int e2 = e - HG * FIN;
    if (e2 < DG * HG) {                  // W_gat [512][256] -> [256][512]
      int n = e2 >> 9, k = e2 & 511;
      float v = Wa[(size_t)k * DG + n];
      ushort h = f2bf(v);
      ah[e2] = h;
      al[e2] = f2bf(v - bf2f(h));
    }
  }
}

// ---------------------------------------------------------------------------
// Split-precision bf16 MFMA GEMM, C^T (feature-major) output:
// C_fm[g][col][node] = (A @ B)^T per graph slab, node = row % 100.
// Structure identical to r5's proven kernel except the epilogue.
// ---------------------------------------------------------------------------
template <int KSH>
__global__ __launch_bounds__(256, 2) void gemm_split_mfma(
    const float* __restrict__ A, const ushort* __restrict__ Bhi_t,
    const ushort* __restrict__ Blo_t, float* __restrict__ C, int M, int N) {
  constexpr int K = 1 << KSH;
  __shared__ ushort Ahi[128 * 32], Alo[128 * 32];
  __shared__ ushort Bsh[256 * 32], Bsl[256 * 32];
  const int tid = threadIdx.x;
  const int lane = tid & 63;
  const int wid = tid >> 6;
  const int wm0 = (wid & 1) * 64;
  const int wn0 = (wid >> 1) * 128;
  const int bm0 = blockIdx.y * 128, bn0 = blockIdx.x * 256;
  const int r16 = lane & 15, g16 = lane >> 4;
  f32x4 acc[4][8] = {};

  for (int k0 = 0; k0 < K; k0 += 32) {
    __syncthreads();
#pragma unroll
    for (int i = 0; i < 4; i++) {
      const int colb = wid * 64 + i * 16;              // wave-uniform
      const int col = colb + (lane >> 2);
      const int rot = (col >> 1) & 3;
      size_t go = (((size_t)(bn0 + col)) << KSH) + k0 + (((lane & 3) ^ rot) << 3);
      gl16(&Bhi_t[go], &Bsh[colb * 32]);
      gl16(&Blo_t[go], &Bsl[colb * 32]);
    }
#pragma unroll
    for (int u = 0; u < 4; u++) {
      int c = tid + u * 256;
      int row = c >> 3, kc = (c & 7) * 4;
      float4 v = *(const float4*)&A[(((size_t)(bm0 + row)) << KSH) + k0 + kc];
      ushort4 h, l;
      h.x = f2bf(v.x); l.x = f2bf(v.x - bf2f(h.x));
      h.y = f2bf(v.y); l.y = f2bf(v.y - bf2f(h.y));
      h.z = f2bf(v.z); l.z = f2bf(v.z - bf2f(h.z));
      h.w = f2bf(v.w); l.w = f2bf(v.w - bf2f(h.w));
      int o = swz(row, kc);
      *(ushort4*)&Ahi[o] = h;
      *(ushort4*)&Alo[o] = l;
    }
    __syncthreads();
    bf16x8 ahf[4], alf[4];
#pragma unroll
    for (int m = 0; m < 4; m++) {
      int o = swz(wm0 + m * 16 + r16, g16 * 8);
      ahf[m] = *(const bf16x8*)&Ahi[o];
      alf[m] = *(const bf16x8*)&Alo[o];
    }
#pragma unroll
    for (int n = 0; n < 8; n++) {
      int o = swz(wn0 + n * 16 + r16, g16 * 8);
      bf16x8 bh = *(const bf16x8*)&Bsh[o];
      bf16x8 bl = *(const bf16x8*)&Bsl[o];
#pragma unroll
      for (int m = 0; m < 4; m++) {
        acc[m][n] = __builtin_amdgcn_mfma_f32_16x16x32_bf16(ahf[m], bh, acc[m][n], 0, 0, 0);
        acc[m][n] = __builtin_amdgcn_mfma_f32_16x16x32_bf16(alf[m], bh, acc[m][n], 0, 0, 0);
        acc[m][n] = __builtin_amdgcn_mfma_f32_16x16x32_bf16(ahf[m], bl, acc[m][n], 0, 0, 0);
      }
    }
  }
  // C^T epilogue: lane holds 4 consecutive rows (nodes) per frag -> float4
  const int crow = g16 * 4;
#pragma unroll
  for (int m = 0; m < 4; m++) {
    int r0 = bm0 + wm0 + m * 16 + crow;
    int gg = r0 / 100;
    int nd = r0 - gg * 100;                      // multiple of 4
#pragma unroll
    for (int n = 0; n < 8; n++) {
      int col = bn0 + wn0 + n * 16 + r16;
      if (nd <= 96) {
        float4 v = {acc[m][n][0], acc[m][n][1], acc[m][n][2], acc[m][n][3]};
        *(float4*)&C[((size_t)gg * N + col) * 100 + nd] = v;
      } else {
#pragma unroll
        for (int q = 0; q < 4; q++) {
          int nd2 = nd + q, g2 = gg;
          if (nd2 >= 100) { nd2 -= 100; g2++; }
          C[((size_t)g2 * N + col) * 100 + nd2] = acc[m][n][q];
        }
      }
    }
  }
}

// ---------------------------------------------------------------------------
// Shared MFMA aggregation core: out[node][NF] = S(112x128, panels) @ B_fm + b
// B_fm = feature-major activations [NF][100] for this graph. 4-term split.
// Called with 256 threads; S panels prebuilt in LDS; Bp* overlay scratch.
// ---------------------------------------------------------------------------
template <int NF, bool RELU>
__device__ __forceinline__ void agg_mfma_core(
    const float* __restrict__ Bfm, const ushort* Sph, const ushort* Spl,
    ushort* Bph, ushort* Bpl, const float* __restrict__ bias,
    float* __restrict__ outg, int tid) {
  const int lane = tid & 63, wid = tid >> 6;
  const int r16 = lane & 15, g16 = lane >> 4;
  for (int c = 0; c < NF / 64; c++) {
    __syncthreads();   // Bp free (prev reads done; first iter: convert done)
    // stage B chunk: 1024 tasks = 4 panels x 64 rows x 4 16B-chunks
    for (int t = tid; t < 1024; t += 256) {
      int p = t >> 8, f = (t >> 2) & 63, ch = t & 3;
      int k0 = p * 32 + ch * 8;
      const float* rb = Bfm + (size_t)(c * 64 + f) * 100;
      float4 v0 = {0.f, 0.f, 0.f, 0.f}, v1 = {0.f, 0.f, 0.f, 0.f};
      if (k0 < 100) v0 = *(const float4*)&rb[k0];
      if (k0 + 4 < 100) v1 = *(const float4*)&rb[k0 + 4];
      u16x8 h, l;
      split8(v0, v1, h, l);
      int o = swz(f, ch * 8);
      *(u16x8*)&Bph[p * 2048 + o] = h;
      *(u16x8*)&Bpl[p * 2048 + o] = l;
    }
    __syncthreads();
    f32x4 acc[7] = {};
#pragma unroll
    for (int ks = 0; ks < 4; ks++) {
      int ob = ks * 2048 + swz(wid * 16 + r16, g16 * 8);
      bf16x8 bh = *(const bf16x8*)&Bph[ob];
      bf16x8 bl = *(const bf16x8*)&Bpl[ob];
#pragma unroll
      for (int mt = 0; mt < 7; mt++) {
        int oa = ks * 3584 + swz(mt * 16 + r16, g16 * 8);
        bf16x8 ah = *(const bf16x8*)&Sph[oa];
        bf16x8 al = *(const bf16x8*)&Spl[oa];
        acc[mt] = __builtin_amdgcn_mfma_f32_16x16x32_bf16(ah, bh, acc[mt], 0, 0, 0);
        acc[mt] = __builtin_amdgcn_mfma_f32_16x16x32_bf16(al, bh, acc[mt], 0, 0, 0);
        acc[mt] = __builtin_amdgcn_mfma_f32_16x16x32_bf16(ah, bl, acc[mt], 0, 0, 0);
        acc[mt] = __builtin_amdgcn_mfma_f32_16x16x32_bf16(al, bl, acc[mt], 0, 0, 0);
      }
    }
    const int col = c * 64 + wid * 16 + r16;
    const float bv = bias[col];
#pragma unroll
    for (int mt = 0; mt < 7; mt++) {
      int row0 = mt * 16 + g16 * 4;
#pragma unroll
      for (int q = 0; q < 4; q++) {
        int row = row0 + q;
        if (row < NN) {
          float v = acc[mt][q] + bv;
          if (RELU) v = fmaxf(v, 0.f);
          outg[(size_t)row * NF + col] = v;
        }
      }
    }
  }
}

// ---------------------------------------------------------------------------
// GCN: build dense normalized adjacency S (112x128) in LDS, then MFMA agg.
// h1[node][512] = relu(S @ h0_fm + b_gcn)
// ---------------------------------------------------------------------------
__global__ __launch_bounds__(256) void gcn_dense(
    const float* __restrict__ h0fm, const int* __restrict__ ei,
    const float* __restrict__ b_gcn, float* __restrict__ h1) {
  const int g = blockIdx.x, tid = threadIdx.x;
  __shared__ __attribute__((aligned(16))) float  Sf32[14336];   // 57344 B
  __shared__ __attribute__((aligned(16))) ushort Sph[14336];    // 28672 B
  __shared__ __attribute__((aligned(16))) ushort Spl[14336];
  __shared__ float dinv[NN];
  __shared__ int   deg[NN];
  ushort* Bph = (ushort*)Sf32;        // overlay: [4][2048] ushorts = 16 KB
  ushort* Bpl = Bph + 8192;
  const int* src = ei + (size_t)g * 2 * NE;
  const int* dst = src + NE;

  for (int i = tid; i < 14336; i += 256) Sf32[i] = 0.f;
  if (tid < NN) deg[tid] = 1;
  __syncthreads();
  for (int e = tid; e < NE; e += 256) atomicAdd(&deg[dst[e]], 1);
  __syncthreads();
  if (tid < NN) dinv[tid] = rsqrtf((float)deg[tid]);
  __syncthreads();
  for (int e = tid; e < NE; e += 256) {
    int s = src[e], d = dst[e];
    atomicAdd(&Sf32[d * 128 + s], dinv[s] * dinv[d]);
  }
  if (tid < NN) atomicAdd(&Sf32[tid * 128 + tid], dinv[tid] * dinv[tid]);
  __syncthreads();
  for (int i = tid; i < 14336; i += 256) {
    int row = i >> 7, k = i & 127;
    float v = Sf32[i];
    ushort h = f2bf(v);
    int o = (k >> 5) * 3584 + swz(row, k & 31);
    Sph[o] = h;
    Spl[o] = f2bf(v - bf2f(h));
  }
  agg_mfma_core<HG, true>(h0fm + (size_t)g * HG * 100, Sph, Spl, Bph, Bpl,
                          b_gcn, h1 + (size_t)g * NN * HG, tid);
}

__device__ inline unsigned fmap(float f) {
  unsigned b = __float_as_uint(f);
  return (b & 0x80000000u) ? ~b : (b | 0x80000000u);
}
__device__ inline float funmap(unsigned u) {
  return __uint_as_float((u & 0x80000000u) ? (u & 0x7fffffffu) : ~u);
}

// ---------------------------------------------------------------------------
// GAT fused: attention (segment softmax by dst) -> dense S_att in LDS ->
// MFMA agg -> gnn[node][256] + patch scores.
// ---------------------------------------------------------------------------
__global__ __launch_bounds__(256) void gat_fused(
    const float* __restrict__ h2fm, const int* __restrict__ ei,
    const float* __restrict__ a_src, const float* __restrict__ a_dst,
    const float* __restrict__ b_gat, float* __restrict__ gnn,
    float* __restrict__ scores) {
  const int g = blockIdx.x, tid = threadIdx.x;
  __shared__ __attribute__((aligned(16))) float  Sf32[14336];
  __shared__ __attribute__((aligned(16))) ushort Sph[14336];
  __shared__ __attribute__((aligned(16))) ushort Spl[14336];
  __shared__ float    sAs[NN], sAd[NN], sSum[NN], sAtt[NN];
  __shared__ unsigned mKey[NN];
  __shared__ int      sCnt[NN];
  __shared__ float    eV[NEL];
  __shared__ float    part[512];
  ushort* Bph = (ushort*)Sf32;
  ushort* Bpl = Bph + 8192;
  const int* src = ei + (size_t)g * 2 * NE;
  const int* dst = src + NE;
  const float* hb = h2fm + (size_t)g * DG * 100;

  for (int i = tid; i < 14336; i += 256) Sf32[i] = 0.f;
  if (tid < NN) { mKey[tid] = 0u; sSum[tid] = 0.f; sAtt[tid] = 0.f; sCnt[tid] = 0; }
  // asrc/adst: coalesced column reads of feature-major h2
  {
    int n = tid & 127, fg = tid >> 7;
    float ps = 0.f, pd = 0.f;
    if (n < NN) {
      for (int f = fg * 128; f < fg * 128 + 128; f++) {
        float hv = hb[(size_t)f * 100 + n];
        ps = fmaf(hv, a_src[f], ps);
        pd = fmaf(hv, a_dst[f], pd);
      }
    }
    part[tid] = ps;
    part[256 + tid] = pd;
  }
  __syncthreads();
  if (tid < NN) {
    sAs[tid] = part[tid] + part[128 + tid];
    sAd[tid] = part[256 + tid] + part[384 + tid];
  }
  __syncthreads();

  for (int i = tid; i < NEL; i += 256) {
    int s, d;
    if (i < NE) { s = src[i]; d = dst[i]; } else { s = d = i - NE; }
    float e = sAs[s] + sAd[d];
    e = (e > 0.f) ? e : NEG_SLOPE * e;
    eV[i] = e;
    atomicMax(&mKey[d], fmap(e));
  }
  __syncthreads();
  for (int i = tid; i < NEL; i += 256) {
    int d = (i < NE) ? dst[i] : i - NE;
    float ex = expf(eV[i] - funmap(mKey[d]));
    eV[i] = ex;
    atomicAdd(&sSum[d], ex);
  }
  __syncthreads();
  for (int i = tid; i < NEL; i += 256) {
    int s, d;
    if (i < NE) { s = src[i]; d = dst[i]; } else { s = d = i - NE; }
    float al = eV[i] / sSum[d];
    atomicAdd(&sAtt[s], al);
    atomicAdd(&sAtt[d], al);
    atomicAdd(&sCnt[s], 1);
    atomicAdd(&sCnt[d], 1);
    atomicAdd(&Sf32[d * 128 + s], al);
  }
  __syncthreads();
  if (tid < NN) scores[g * NN + tid] = sAtt[tid] / (float)sCnt[tid];
  for (int i = tid; i < 14336; i += 256) {
    int row = i >> 7, k = i & 127;
    float v = Sf32[i];
    ushort h = f2bf(v);
    int o = (k >> 5) * 3584 + swz(row, k & 31);
    Sph[o] = h;
    Spl[o] = f2bf(v - bf2f(h));
  }
  agg_mfma_core<DG, false>(hb, Sph, Spl, Bph, Bpl, b_gat,
                           gnn + (size_t)g * NN * DG, tid);
}

// ---------------------------------------------------------------------------
// Radix-select top-50 of 25600 (1 block, 1024 thr). Parallel suffix scan.
// ---------------------------------------------------------------------------
__global__ __launch_bounds__(1024) void topk_radix(
    const float* __restrict__ scores, int* __restrict__ topk) {
  const int tid = threadIdx.x;
  unsigned key[25];
#pragma unroll
  for (int u = 0; u < 25; u++) key[u] = fmap(scores[tid + u * 1024]);

  __shared__ unsigned hist[16][256];
  __shared__ unsigned total[256], suff[257];
  __shared__ unsigned sPref;
  __shared__ int sNeed;
  const int wv = tid >> 6;
  unsigned pref = 0;
  int plen = 0, need = KTOP;
  for (int pass = 0; pass < 4; pass++) {
    const int shift = 24 - 8 * pass;
    for (int i = tid; i < 16 * 256; i += 1024) ((unsigned*)hist)[i] = 0;
    __syncthreads();
#pragma unroll
    for (int u = 0; u < 25; u++) {
      unsigned k = key[u];
      bool ok = (plen == 0) || ((k >> (32 - plen)) == (pref >> (32 - plen)));
      if (ok) atomicAdd(&hist[wv][(k >> shift) & 255], 1u);
    }
    __syncthreads();
    if (tid < 256) {
      unsigned s = 0;
#pragma unroll
      for (int w = 0; w < 16; w++) s += hist[w][tid];
      total[tid] = s;
      suff[tid] = s;
      if (tid == 0) suff[256] = 0;
    }
    __syncthreads();
    for (int st = 1; st < 256; st <<= 1) {
      unsigned v = 0;
      if (tid < 256) v = suff[tid] + ((tid + st < 256) ? suff[tid + st] : 0u);
      __syncthreads();
      if (tid < 256) suff[tid] = v;
      __syncthreads();
    }
    if (tid < 256) {
      unsigned s1 = suff[tid + 1];
      if (suff[tid] >= (unsigned)need && s1 < (unsigned)need) {
        sPref = pref | ((unsigned)tid << shift);
        sNeed = need - (int)s1;
      }
    }
    __syncthreads();
    pref = sPref;
    need = sNeed;
    plen += 8;
    __syncthreads();
  }

  const unsigned thr = pref;
  __shared__ int nGt;
  __shared__ unsigned long long cand[64];
  __shared__ int eqMin;
  if (tid == 0) nGt = 0;
  __syncthreads();
  unsigned eqmask = 0;
#pragma unroll
  for (int u = 0; u < 25; u++) {
    unsigned k = key[u];
    if (k > thr) {
      int p = atomicAdd(&nGt, 1);
      cand[p] = ((unsigned long long)k << 32) | (unsigned)(~(tid + u * 1024));
    } else if (k == thr) {
      eqmask |= 1u << u;
    }
  }
  __syncthreads();
  const int base = nGt;
  for (int r = 0; r < need; r++) {
    if (tid == 0) eqMin = 0x7fffffff;
    __syncthreads();
    int mymin = 0x7fffffff;
    unsigned mm = eqmask;
    while (mm) {
      int u = __ffs(mm) - 1;
      mm &= mm - 1;
      int idx = tid + u * 1024;
      if (idx < mymin) mymin = idx;
    }
#pragma unroll
    for (int o = 32; o; o >>= 1) {
      int ot = __shfl_down(mymin, o);
      if (ot < mymin) mymin = ot;
    }
    if ((tid & 63) == 0 && mymin != 0x7fffffff) atomicMin(&eqMin, mymin);
    __syncthreads();
    int sel = eqMin;
    if (tid == 0) topk[base + r] = sel;
    if ((sel & 1023) == tid) eqmask &= ~(1u << (sel >> 10));
    __syncthreads();
  }
  if (tid < 64) {
    unsigned long long c = (tid < base) ? cand[tid] : 0ull;
    for (int r = 0; r < base; r++) {
      unsigned long long m = c;
#pragma unroll
      for (int o = 32; o; o >>= 1) {
        unsigned long long t2 = __shfl_down(m, o);
        if (t2 > m) m = t2;
      }
      m = __shfl(m, 0);
      if (tid == 0) topk[r] = (int)(~(unsigned)m);
      if (c == m) c = 0ull;
    }
  }
}

// ---------------------------------------------------------------------------
// Project the 50 selected rows: out[i,:] = gnn[idx[i],:] @ W_proj + b_proj
// ---------------------------------------------------------------------------
__global__ __launch_bounds__(256) void proj_kernel(
    const float* __restrict__ gnn, const int* __restrict__ topk,
    const float* __restrict__ Wp, const float* __restrict__ bp,
    float* __restrict__ outp) {
  const int bi = blockIdx.x >> 2;
  const int c0 = (blockIdx.x & 3) * 256;
  const int tid = threadIdx.x;
  __shared__ float row[DG];
  const int node = topk[bi];
  row[tid] = gnn[(size_t)node * DG + tid];
  __syncthreads();
  float acc = 0.f;
#pragma unroll 8
  for (int k = 0; k < DG; k++)
    acc = fmaf(row[k], Wp[(size_t)k * PO + c0 + tid], acc);
  outp[(size_t)bi * PO + c0 + tid] = acc + bp[c0 + tid];
}

// ---------------------------------------------------------------------------
extern "C" void kernel_launch(void* const* d_in, const int* in_sizes, int n_in,
                              void* d_out, int out_size, void* d_ws,
                              size_t ws_size, hipStream_t stream) {
  const float* x      = (const float*)d_in[0];
  const int*   ei     = (const int*)d_in[1];
  const float* W_gcn  = (const float*)d_in[2];
  const float* b_gcn  = (const float*)d_in[3];
  const float* W_gat  = (const float*)d_in[4];
  const float* b_gat  = (const float*)d_in[5];
  const float* a_src  = (const float*)d_in[6];
  const float* a_dst  = (const float*)d_in[7];
  const float* W_proj = (const float*)d_in[8];
  const float* b_proj = (const float*)d_in[9];
  float* outp = (float*)d_out;

  // workspace (~110 MB):
  //  [0, 52.4M)        h0_fm f32 [256][512][100]; dead after gcn_dense, then
  //                    h2_fm [256][256][100] at [0,26.2M), gnn at [26.2,52.4M)
  //  [52.4M, 104.9M)   h1 f32 [25600][512]
  //  [104.9M, ...)     weights hi/lo, scores, topk
  char* ws = (char*)d_ws;
  float*  h0fm     = (float*)ws;
  float*  h2fm     = (float*)ws;
  float*  gnn      = (float*)(ws + 26214400);
  float*  h1       = (float*)(ws + 52428800);
  char*   wsc      = ws + 104857600;
  ushort* WgcnT_hi = (ushort*)(wsc);
  ushort* WgcnT_lo = (ushort*)(wsc + 2097152);
  ushort* WgatT_hi = (ushort*)(wsc + 4194304);
  ushort* WgatT_lo = (ushort*)(wsc + 4456448);
  float*  scores   = (float*)(wsc + 4718592);
  int*    topk     = (int*)(wsc + 4820992);

  const int M = NB * NN;  // 25600

  tsplit_both<<<(HG * FIN + DG * HG + 255) / 256, 256, 0, stream>>>(
      W_gcn, WgcnT_hi, WgcnT_lo, W_gat, WgatT_hi, WgatT_lo);
  // h0_fm = (x @ W_gcn)^T per graph   [25600,2048]x[2048,512]
  gemm_split_mfma<11><<<dim3(HG / 256, M / 128), 256, 0, stream>>>(
      x, WgcnT_hi, WgcnT_lo, h0fm, M, HG);
  // h1 = relu(S_gcn @ h0 + b_gcn)  (dense-S MFMA, node-major out)
  gcn_dense<<<NB, 256, 0, stream>>>(h0fm, ei, b_gcn, h1);
  // h2_fm = (h1 @ W_gat)^T per graph  [25600,512]x[512,256]
  gemm_split_mfma<9><<<dim3(DG / 256, M / 128), 256, 0, stream>>>(
      h1, WgatT_hi, WgatT_lo, h2fm, M, DG);
  // GAT attention + dense-S MFMA aggregation + scores
  gat_fused<<<NB, 256, 0, stream>>>(h2fm, ei, a_src, a_dst, b_gat, gnn,
                                    scores);
  // top-50
  topk_radix<<<1, 1024, 0, stream>>>(scores, topk);
  // project selected rows
  proj_kernel<<<KTOP * 4, 256, 0, stream>>>(gnn, topk, W_proj, b_proj, outp);
}